// Round 5
// baseline (253.063 us; speedup 1.0000x reference)
//
#include <hip/hip_runtime.h>

typedef unsigned short u16;
typedef unsigned int u32;

#define D_MODEL 1024
#define N_HEADS 16
#define D_HEAD 64
#define WIN 256
#define SEQ 2048
#define BATCH 2
#define NROWS (BATCH*SEQ)          // 4096 token rows

typedef short frag_ab __attribute__((ext_vector_type(8)));   // 8 bf16 (4 VGPRs)
typedef float frag_cd __attribute__((ext_vector_type(4)));   // 4 fp32 (16x16 C/D)
typedef float f32x16 __attribute__((ext_vector_type(16)));   // 32x32 C/D
typedef u16 u16x8 __attribute__((ext_vector_type(8)));

__device__ __forceinline__ u16 f2bf(float f) {
    union { float f; u32 u; } x; x.f = f;
    u32 r = x.u + 0x7fffu + ((x.u >> 16) & 1u);   // RNE
    return (u16)(r >> 16);
}

__device__ __forceinline__ void load_lds16(const void* g, void* l) {
    __builtin_amdgcn_global_load_lds(
        (const __attribute__((address_space(1))) void*)g,
        (__attribute__((address_space(3))) void*)l, 16, 0, 0);
}

// ---------------- transpose-cast tile helper (caller supplies LDS) ----------------
__device__ __forceinline__ void transpose_tile(const float* __restrict__ W, u16* __restrict__ WT,
                                               int K, int N, int n0, int k0,
                                               int scale_rows, float scale, float (*tile)[33]) {
    int x = threadIdx.x & 31, y = threadIdx.x >> 5;   // 32 x 8
#pragma unroll
    for (int r = 0; r < 4; r++)
        tile[y + 8 * r][x] = W[(size_t)(k0 + y + 8 * r) * N + n0 + x];
    __syncthreads();
#pragma unroll
    for (int r = 0; r < 4; r++) {
        int nrow = n0 + y + 8 * r;
        float v = tile[x][y + 8 * r];
        if (nrow < scale_rows) v *= scale;
        WT[(size_t)nrow * K + k0 + x] = f2bf(v);
    }
}

// ---------------- prep: cast x + transpose-cast W_qkv + W_out ----------------
__global__ __launch_bounds__(256) void prep_kernel(const float* __restrict__ x,
                                                   const float* __restrict__ W_qkv,
                                                   const float* __restrict__ W_out,
                                                   u16* __restrict__ xb,
                                                   u16* __restrict__ wqkvT,
                                                   u16* __restrict__ woutT,
                                                   float qscale) {
    __shared__ float tile[32][33];
    const int bid = blockIdx.x;
    if (bid < 4096) {
        int idx = bid * 256 + threadIdx.x;
        float4 v = ((const float4*)x)[idx];
        ushort4 o;
        o.x = f2bf(v.x); o.y = f2bf(v.y); o.z = f2bf(v.z); o.w = f2bf(v.w);
        ((ushort4*)xb)[idx] = o;
    } else if (bid < 7168) {
        int t = bid - 4096;                       // W_qkv: 96 x 32 tiles of 32x32
        transpose_tile(W_qkv, wqkvT, D_MODEL, 3 * D_MODEL, (t % 96) * 32, (t / 96) * 32,
                       D_MODEL, qscale, tile);
    } else {
        int t = bid - 7168;                       // W_out: 32 x 32 tiles
        transpose_tile(W_out, woutT, D_MODEL, D_MODEL, (t & 31) * 32, (t >> 5) * 32,
                       0, 1.0f, tile);
    }
}

// ---------------- bf16 GEMM: C[BM x 128] = A[M,K] * BT[N,K]^T, BK=64, 32x32x16 ----------------
// Proven m97-family structure (round-0 verified). `reps` > 1 repeats the whole
// computation idempotently (ATTRIBUTION ONLY: surfaces this dispatch above the
// ~43us harness fills in rocprof top-5; single-shot time = dur/reps).
template <bool BF16_OUT, int BM, int MB, int NPER>
__global__ __launch_bounds__(256, 4) void gemm_bk64(const u16* __restrict__ A,
                                                    const u16* __restrict__ BT,
                                                    void* __restrict__ C,
                                                    int M, int N, int K, int reps) {
    constexpr int MT = BM / 64;
    __shared__ union SMem {
        struct { u16 As[BM * 64]; u16 Bs[128 * 64]; } s;
        u16 cs[BF16_OUT ? BM * 136 : 1];          // epilogue transpose tile (bf16 path)
    } sm;
    const int tid = threadIdx.x;
    const int xcd = blockIdx.x & 7, sblk = blockIdx.x >> 3;
    const int m0 = (sblk % MB) * BM;
    const int n0 = (xcd * NPER + sblk / MB) * 128;
    const int wave = tid >> 6, lane = tid & 63;
    const int wm = (wave >> 1) * (BM / 2), wn = (wave & 1) * 64;
    const int l32 = lane & 31, kh = lane >> 5;

    const int r0 = tid >> 3;                   // 0..31
    const int w  = (tid & 7) ^ (r0 & 7);       // swizzled source chunk
    const u16* aP = A  + (size_t)(m0 + r0) * K + w * 8;
    const u16* bP = BT + (size_t)(n0 + r0) * K + w * 8;

#pragma unroll 1
    for (int rep = 0; rep < reps; ++rep) {
        f32x16 acc[MT][2] = {};

        for (int k0 = 0; k0 < K; k0 += 64) {
            __syncthreads();
#pragma unroll
            for (int u = 0; u < BM / 32; u++)
                load_lds16(aP + (size_t)(32 * u) * K + k0, &sm.s.As[(tid + 256 * u) * 8]);
#pragma unroll
            for (int u = 0; u < 4; u++)
                load_lds16(bP + (size_t)(32 * u) * K + k0, &sm.s.Bs[(tid + 256 * u) * 8]);
            __syncthreads();

#pragma unroll
            for (int kk = 0; kk < 4; kk++) {
                const int csel = ((kk * 2 + kh) ^ (l32 & 7)) * 8;
                frag_ab af[MT], bf[2];
#pragma unroll
                for (int t = 0; t < MT; t++)
                    af[t] = *(const frag_ab*)&sm.s.As[(wm + t * 32 + l32) * 64 + csel];
#pragma unroll
                for (int t = 0; t < 2; t++)
                    bf[t] = *(const frag_ab*)&sm.s.Bs[(wn + t * 32 + l32) * 64 + csel];
#pragma unroll
                for (int mt = 0; mt < MT; mt++)
#pragma unroll
                    for (int nt = 0; nt < 2; nt++)
                        acc[mt][nt] = __builtin_amdgcn_mfma_f32_32x32x16_bf16(af[mt], bf[nt], acc[mt][nt], 0, 0, 0);
            }
        }

        if constexpr (BF16_OUT) {
            __syncthreads();
#pragma unroll
            for (int mt = 0; mt < MT; mt++)
#pragma unroll
                for (int nt = 0; nt < 2; nt++) {
                    int col = wn + nt * 32 + l32;
#pragma unroll
                    for (int reg = 0; reg < 16; reg++) {
                        int row = wm + mt * 32 + (reg & 3) + 8 * (reg >> 2) + 4 * kh;
                        sm.cs[row * 136 + col] = f2bf(acc[mt][nt][reg]);
                    }
                }
            __syncthreads();
            const int cc = tid & 15, rb = tid >> 4;
#pragma unroll
            for (int i = 0; i < BM / 16; i++) {
                int row = rb + 16 * i;
                u16x8 vv = *(const u16x8*)&sm.cs[row * 136 + cc * 8];
                *(u16x8*)((u16*)C + (size_t)(m0 + row) * N + n0 + cc * 8) = vv;
            }
        } else {
#pragma unroll
            for (int mt = 0; mt < MT; mt++)
#pragma unroll
                for (int nt = 0; nt < 2; nt++) {
                    int col = n0 + wn + nt * 32 + l32;
#pragma unroll
                    for (int reg = 0; reg < 16; reg++) {
                        int row = m0 + wm + mt * 32 + (reg & 3) + 8 * (reg >> 2) + 4 * kh;
                        ((float*)C)[(size_t)row * N + col] = acc[mt][nt][reg];
                    }
                }
        }
    }
}

// ---------------- MFMA flash attention (sliding window), pipelined ----------------
// 1024 blocks: decode head=B&31, qc=B>>5 -> all 32 q-tiles of a head land on
// XCD head%8; per-XCD KV working set = 4 heads x 512 KB = 2 MB, L2-resident.
// `reps` repeats the whole computation idempotently (attribution only).
__global__ __launch_bounds__(256) void attn_kernel(const u16* __restrict__ qkv,
                                                   u16* __restrict__ out, int reps) {
    __shared__ u16 Ks[2][64 * 64];       // XOR-chunk-swizzled: chunk c of row r at c^(r&7)
    __shared__ u16 Vt[64 * 72];          // Vt[d][j], row pad +8 (single buffer)
    __shared__ u16 ps[4][16 * 72];       // per-wave P tile, row pad +8

    const int tid = threadIdx.x;
    const int wave = tid >> 6, lane = tid & 63;
    const int quad = lane >> 4, c16 = lane & 15;

    const int bh = blockIdx.x & 31;      // b*16+h  -> XCD = bh%8
    const int qc = blockIdx.x >> 5;      // 0..31
    const int h  = bh & 15;
    const int b  = bh >> 4;
    const int q0 = qc * 64;
    const int qw0 = q0 + wave * 16;

    frag_ab qf[2];
    {
        const u16* qrow = qkv + (size_t)(b * SEQ + qw0 + c16) * 3072 + h * 64;
        qf[0] = *(const frag_ab*)(qrow + quad * 8);
        qf[1] = *(const frag_ab*)(qrow + 32 + quad * 8);
    }

    const int ntiles = qc < 4 ? qc + 1 : 5;

    const int krow = wave * 16 + (lane >> 3);
    const int kchunk = (lane & 7) ^ (lane >> 3);
    const int vj2 = (tid & 31) * 2, vd8 = tid >> 5;

    const u16* kbase = qkv + (size_t)(b * SEQ + krow) * 3072 + 1024 + h * 64 + kchunk * 8;
    const u16* vbase = qkv + (size_t)(b * SEQ + vj2) * 3072 + 2048 + h * 64 + vd8 * 8;

#pragma unroll 1
    for (int rep = 0; rep < reps; ++rep) {
        __syncthreads();                 // WAR: prior rep's PV reads done before restaging

        float m_r[4], l_r[4];
        frag_cd acc[4] = {};
        u16x8 va, vb;
        {
            const u16* g = kbase + (size_t)q0 * 3072;
            load_lds16(g,            &Ks[0][krow * 64 + (lane & 7) * 8]);
            load_lds16(g + 8 * 3072, &Ks[0][(krow + 8) * 64 + (lane & 7) * 8]);
            const u16* gv = vbase + (size_t)q0 * 3072;
            va = *(const u16x8*)gv;
            vb = *(const u16x8*)(gv + 3072);
#pragma unroll
            for (int dd = 0; dd < 8; dd++)
                *(u32*)&Vt[(vd8 * 8 + dd) * 72 + vj2] = (u32)va[dd] | ((u32)vb[dd] << 16);
        }

        for (int t = 0; t < ntiles; t++) {
            const int cur = t & 1, nxt = cur ^ 1;
            const int j0 = q0 - 64 * t;
            __syncthreads();             // Ks[cur] + Vt staged & visible
            const bool pre = (t + 1 < ntiles);
            if (pre) {                   // prefetch t+1: K -> LDS[nxt] (async), V -> regs
                const u16* g = kbase + (size_t)(j0 - 64) * 3072;
                load_lds16(g,            &Ks[nxt][krow * 64 + (lane & 7) * 8]);
                load_lds16(g + 8 * 3072, &Ks[nxt][(krow + 8) * 64 + (lane & 7) * 8]);
                const u16* gv = vbase + (size_t)(j0 - 64) * 3072;
                va = *(const u16x8*)gv;
                vb = *(const u16x8*)(gv + 3072);
            }

            frag_cd s[4] = {};
#pragma unroll
            for (int kb = 0; kb < 4; kb++) {
                frag_ab kf0 = *(const frag_ab*)&Ks[cur][(kb * 16 + c16) * 64 + ((quad    ) ^ (c16 & 7)) * 8];
                frag_ab kf1 = *(const frag_ab*)&Ks[cur][(kb * 16 + c16) * 64 + ((4 + quad) ^ (c16 & 7)) * 8];
                s[kb] = __builtin_amdgcn_mfma_f32_16x16x32_bf16(qf[0], kf0, s[kb], 0, 0, 0);
                s[kb] = __builtin_amdgcn_mfma_f32_16x16x32_bf16(qf[1], kf1, s[kb], 0, 0, 0);
            }

            if (t == 0) {
#pragma unroll
                for (int reg = 0; reg < 4; reg++) {
                    const int i = qw0 + quad * 4 + reg;
#pragma unroll
                    for (int kb = 0; kb < 4; kb++)
                        if (q0 + kb * 16 + c16 > i) s[kb][reg] = -1e30f;
                }
            } else if (t == 4) {
#pragma unroll
                for (int reg = 0; reg < 4; reg++) {
                    const int i = qw0 + quad * 4 + reg;
#pragma unroll
                    for (int kb = 0; kb < 4; kb++)
                        if (j0 + kb * 16 + c16 + WIN <= i) s[kb][reg] = -1e30f;
                }
            }

            float mt_[4];
#pragma unroll
            for (int reg = 0; reg < 4; reg++)
                mt_[reg] = fmaxf(fmaxf(s[0][reg], s[1][reg]), fmaxf(s[2][reg], s[3][reg]));
#pragma unroll
            for (int off = 1; off < 16; off <<= 1)
#pragma unroll
                for (int reg = 0; reg < 4; reg++) mt_[reg] = fmaxf(mt_[reg], __shfl_xor(mt_[reg], off));

            float alpha[4];
            if (t == 0) {
#pragma unroll
                for (int reg = 0; reg < 4; reg++) m_r[reg] = mt_[reg];
            } else {
#pragma unroll
                for (int reg = 0; reg < 4; reg++) {
                    float mn = fmaxf(m_r[reg], mt_[reg]);
                    alpha[reg] = __builtin_amdgcn_exp2f(m_r[reg] - mn);
                    m_r[reg] = mn;
                }
            }

            float rs[4] = {0.f, 0.f, 0.f, 0.f};
#pragma unroll
            for (int kb = 0; kb < 4; kb++)
#pragma unroll
                for (int reg = 0; reg < 4; reg++) {
                    float p = __builtin_amdgcn_exp2f(s[kb][reg] - m_r[reg]);
                    union { float f; u32 u; } pu; pu.f = p;
                    ps[wave][(quad * 4 + reg) * 72 + kb * 16 + c16] = (u16)(pu.u >> 16);  // RTZ
                    rs[reg] += p;
                }
#pragma unroll
            for (int off = 1; off < 16; off <<= 1)
#pragma unroll
                for (int reg = 0; reg < 4; reg++) rs[reg] += __shfl_xor(rs[reg], off);

            if (t == 0) {
#pragma unroll
                for (int reg = 0; reg < 4; reg++) l_r[reg] = rs[reg];
            } else {
#pragma unroll
                for (int reg = 0; reg < 4; reg++) l_r[reg] = l_r[reg] * alpha[reg] + rs[reg];
#pragma unroll
                for (int dblk = 0; dblk < 4; dblk++)
#pragma unroll
                    for (int reg = 0; reg < 4; reg++) acc[dblk][reg] *= alpha[reg];
            }

#pragma unroll
            for (int js = 0; js < 2; js++) {
                frag_ab pf = *(const frag_ab*)&ps[wave][c16 * 72 + js * 32 + quad * 8];
#pragma unroll
                for (int dblk = 0; dblk < 4; dblk++) {
                    frag_ab vf = *(const frag_ab*)&Vt[(dblk * 16 + c16) * 72 + js * 32 + quad * 8];
                    acc[dblk] = __builtin_amdgcn_mfma_f32_16x16x32_bf16(pf, vf, acc[dblk], 0, 0, 0);
                }
            }

            if (pre) {
                __syncthreads();         // all waves done with PV(t) -> Vt overwrite safe
#pragma unroll
                for (int dd = 0; dd < 8; dd++)
                    *(u32*)&Vt[(vd8 * 8 + dd) * 72 + vj2] = (u32)va[dd] | ((u32)vb[dd] << 16);
            }
        }

        float inv[4];
#pragma unroll
        for (int reg = 0; reg < 4; reg++) inv[reg] = 1.f / l_r[reg];
#pragma unroll
        for (int dblk = 0; dblk < 4; dblk++)
#pragma unroll
            for (int reg = 0; reg < 4; reg++)
                out[(size_t)(b * SEQ + qw0 + quad * 4 + reg) * 1024 + h * 64 + dblk * 16 + c16] =
                    f2bf(acc[dblk][reg] * inv[reg]);
    }
}

extern "C" void kernel_launch(void* const* d_in, const int* in_sizes, int n_in,
                              void* d_out, int out_size, void* d_ws, size_t ws_size,
                              hipStream_t stream) {
    const float* x     = (const float*)d_in[0];   // [2,2048,1024]
    const float* W_qkv = (const float*)d_in[1];   // [1024,3072]
    const float* W_out = (const float*)d_in[2];   // [1024,1024]
    float* out = (float*)d_out;                   // [2,2048,1024]

    char* ws = (char*)d_ws;
    u16* xb    = (u16*)(ws);                       //  8 MB : x bf16 [4096,1024]
    u16* wqkvT = (u16*)(ws + 8388608);             //  6 MB : W_qkv^T bf16 [3072,1024] (q rows pre-scaled)
    u16* woutT = (u16*)(ws + 14680064);            //  2 MB : W_out^T bf16 [1024,1024]
    u16* qkvb  = (u16*)(ws + 16777216);            // 24 MB : qkv bf16 [4096,3072]
    u16* attnb = (u16*)(ws + 41943040);            //  8 MB : attn out bf16 [4096,1024]

    const float QSCALE = 0.125f * 1.4426950408889634f;  // 1/sqrt(64) * log2(e)

    // ===== ATTRIBUTION ROUND: reps>1 on the three main kernels (idempotent). =====
    // Single-shot stage time = dispatch_dur / reps; round 6 reverts reps to 1.
    prep_kernel<<<8192, 256, 0, stream>>>(x, W_qkv, W_out, xb, wqkvT, woutT, QSCALE);
    // gemm1 x2: qkv = xb @ wqkvT^T. 768 blocks (3/CU), round-0-proven config.
    gemm_bk64<true, 128, 32, 3><<<768, 256, 0, stream>>>(
        xb, wqkvT, qkvb, NROWS, 3 * D_MODEL, D_MODEL, 2);
    // attn x3: 1024 blocks (4/CU), head-per-XCD swizzle.
    attn_kernel<<<1024, 256, 0, stream>>>(qkvb, attnb, 3);
    // gemm2 x3: out = attnb @ woutT^T. Round-0 config (BM=64, 512 blocks, 2/CU).
    gemm_bk64<false, 64, 64, 1><<<512, 256, 0, stream>>>(
        attnb, woutT, out, NROWS, D_MODEL, D_MODEL, 3);
}

// Round 6
// 147.966 us; speedup vs baseline: 1.7103x; 1.7103x over previous
//
#include <hip/hip_runtime.h>

typedef unsigned short u16;
typedef unsigned int u32;

#define D_MODEL 1024
#define N_HEADS 16
#define D_HEAD 64
#define WIN 256
#define SEQ 2048
#define BATCH 2
#define NROWS (BATCH*SEQ)          // 4096 token rows

typedef short frag_ab __attribute__((ext_vector_type(8)));   // 8 bf16 (4 VGPRs)
typedef float frag_cd __attribute__((ext_vector_type(4)));   // 4 fp32 (16x16 C/D)
typedef float f32x16 __attribute__((ext_vector_type(16)));   // 32x32 C/D
typedef u16 u16x8 __attribute__((ext_vector_type(8)));

__device__ __forceinline__ u16 f2bf(float f) {
    union { float f; u32 u; } x; x.f = f;
    u32 r = x.u + 0x7fffu + ((x.u >> 16) & 1u);   // RNE
    return (u16)(r >> 16);
}

__device__ __forceinline__ void load_lds16(const void* g, void* l) {
    __builtin_amdgcn_global_load_lds(
        (const __attribute__((address_space(1))) void*)g,
        (__attribute__((address_space(3))) void*)l, 16, 0, 0);
}

// ---------------- transpose-cast tile helper (caller supplies LDS) ----------------
__device__ __forceinline__ void transpose_tile(const float* __restrict__ W, u16* __restrict__ WT,
                                               int K, int N, int n0, int k0,
                                               int scale_rows, float scale, float (*tile)[33]) {
    int x = threadIdx.x & 31, y = threadIdx.x >> 5;   // 32 x 8
#pragma unroll
    for (int r = 0; r < 4; r++)
        tile[y + 8 * r][x] = W[(size_t)(k0 + y + 8 * r) * N + n0 + x];
    __syncthreads();
#pragma unroll
    for (int r = 0; r < 4; r++) {
        int nrow = n0 + y + 8 * r;
        float v = tile[x][y + 8 * r];
        if (nrow < scale_rows) v *= scale;
        WT[(size_t)nrow * K + k0 + x] = f2bf(v);
    }
}

// ---------------- prep: cast x + transpose-cast W_qkv (r0-exact) ----------------
__global__ __launch_bounds__(256) void prep_kernel(const float* __restrict__ x,
                                                   const float* __restrict__ W_qkv,
                                                   u16* __restrict__ xb,
                                                   u16* __restrict__ wqkvT,
                                                   float qscale) {
    __shared__ float tile[32][33];
    const int bid = blockIdx.x;
    if (bid < 4096) {
        int idx = bid * 256 + threadIdx.x;
        float4 v = ((const float4*)x)[idx];
        ushort4 o;
        o.x = f2bf(v.x); o.y = f2bf(v.y); o.z = f2bf(v.z); o.w = f2bf(v.w);
        ((ushort4*)xb)[idx] = o;
    } else {
        int t = bid - 4096;                       // N=3072: 96 x 32 tiles
        transpose_tile(W_qkv, wqkvT, D_MODEL, 3 * D_MODEL, (t % 96) * 32, (t / 96) * 32,
                       D_MODEL, qscale, tile);
    }
}

// ---------------- gemm1: qkv = xb @ wqkvT^T. BM=128, BN=96, 16x16x32 frags ----------------
// Theory (r5 counters): the 32x32 2x2-blocked version is LDS-read-bound
// (1.0 ds_read_b128 per MFMA, MfmaUtil 27%). 16x16x32 with 4x3 per-wave blocking
// cuts reads/MFMA to 7/12=0.58 (reads ~ perimeter, MFMA ~ area), and BN=96 gives
// grid = 32m x 32n = 1024 blocks = 4/CU (vs 3/CU at BN=128).
// Fragment maps are the ones already verified IN THIS FILE: A/B frag = attn's
// qf/kf pattern (lane m=c16, k=quad*8+j per 32-slice; LDS slot for source chunk
// sc of row r is sc^(r&7)); C/D col=lane&15, row=quad*4+reg [m89/m91].
// Schedule/staging/barriers identical to the proven gemm_bk64 (2-sync per K-step).
__global__ __launch_bounds__(256, 4) void gemm1_96(const u16* __restrict__ A,
                                                   const u16* __restrict__ BT,
                                                   u16* __restrict__ C) {
    constexpr int K = 1024, N = 3072;
    __shared__ union SMem {
        struct { u16 As[128 * 64]; u16 Bs[96 * 64]; } s;   // 16 KB + 12 KB
        u16 cs[128 * 104];                                 // epilogue transpose (26.6 KB)
    } sm;
    const int tid = threadIdx.x;
    const int xcd = blockIdx.x & 7, sblk = blockIdx.x >> 3;
    const int m0 = (sblk & 31) * 128;                 // 32 m-blocks
    const int n0 = (xcd * 4 + (sblk >> 5)) * 96;      // 8 XCD x 4 n-blocks (B-panel 768 KB/XCD)
    const int wave = tid >> 6, lane = tid & 63;
    const int quad = lane >> 4, c16 = lane & 15;
    const int wm = (wave >> 1) * 64, wn = (wave & 1) * 48;

    const int r0 = tid >> 3;                   // 0..31
    const int w  = (tid & 7) ^ (r0 & 7);       // swizzled source chunk
    const u16* aP = A  + (size_t)(m0 + r0) * K + w * 8;
    const u16* bP = BT + (size_t)(n0 + r0) * K + w * 8;

    frag_cd acc[4][3] = {};                    // 4x3 of 16x16 -> 64x48 per wave

    for (int k0 = 0; k0 < K; k0 += 64) {
        __syncthreads();                       // WAR: prev iteration's reads done
#pragma unroll
        for (int u = 0; u < 4; u++)            // A: 128 rows
            load_lds16(aP + (size_t)(32 * u) * K + k0, &sm.s.As[(tid + 256 * u) * 8]);
#pragma unroll
        for (int u = 0; u < 3; u++)            // B: 96 rows
            load_lds16(bP + (size_t)(32 * u) * K + k0, &sm.s.Bs[(tid + 256 * u) * 8]);
        __syncthreads();                       // deposits visible

#pragma unroll
        for (int kk = 0; kk < 2; kk++) {       // two K=32 slices
            const int csel = ((kk * 4 + quad) ^ (c16 & 7)) * 8;
            frag_ab af[4], bf[3];
#pragma unroll
            for (int fm = 0; fm < 4; fm++)
                af[fm] = *(const frag_ab*)&sm.s.As[(wm + fm * 16 + c16) * 64 + csel];
#pragma unroll
            for (int fn = 0; fn < 3; fn++)
                bf[fn] = *(const frag_ab*)&sm.s.Bs[(wn + fn * 16 + c16) * 64 + csel];
#pragma unroll
            for (int fm = 0; fm < 4; fm++)
#pragma unroll
                for (int fn = 0; fn < 3; fn++)
                    acc[fm][fn] = __builtin_amdgcn_mfma_f32_16x16x32_bf16(
                        af[fm], bf[fn], acc[fm][fn], 0, 0, 0);
        }
    }

    // epilogue: acc -> LDS (row-major bf16) -> vectorized store
    __syncthreads();
#pragma unroll
    for (int fm = 0; fm < 4; fm++)
#pragma unroll
        for (int fn = 0; fn < 3; fn++) {
            const int col = wn + fn * 16 + c16;
#pragma unroll
            for (int reg = 0; reg < 4; reg++) {
                const int row = wm + fm * 16 + quad * 4 + reg;   // C/D map m89/m91
                sm.cs[row * 104 + col] = f2bf(acc[fm][fn][reg]);
            }
        }
    __syncthreads();
#pragma unroll
    for (int i = 0; i < 6; i++) {              // 128 rows x 12 chunks of 8
        const int idx = tid + 256 * i;
        const int row = idx / 12, c8 = idx % 12;
        u16x8 vv = *(const u16x8*)&sm.cs[row * 104 + c8 * 8];
        *(u16x8*)(C + (size_t)(m0 + row) * N + n0 + c8 * 8) = vv;
    }
}

// ---------------- bf16 GEMM (r0-exact; used for gemm2) ----------------
template <bool BF16_OUT, int BM, int MB, int NPER>
__global__ __launch_bounds__(256, 4) void gemm_bk64(const u16* __restrict__ A,
                                                    const u16* __restrict__ BT,
                                                    void* __restrict__ C,
                                                    int M, int N, int K) {
    constexpr int MT = BM / 64;
    __shared__ union SMem {
        struct { u16 As[BM * 64]; u16 Bs[128 * 64]; } s;
        u16 cs[BF16_OUT ? BM * 136 : 1];
    } sm;
    const int tid = threadIdx.x;
    const int xcd = blockIdx.x & 7, sblk = blockIdx.x >> 3;
    const int m0 = (sblk % MB) * BM;
    const int n0 = (xcd * NPER + sblk / MB) * 128;
    const int wave = tid >> 6, lane = tid & 63;
    const int wm = (wave >> 1) * (BM / 2), wn = (wave & 1) * 64;
    const int l32 = lane & 31, kh = lane >> 5;

    f32x16 acc[MT][2] = {};

    const int r0 = tid >> 3;                   // 0..31
    const int w  = (tid & 7) ^ (r0 & 7);       // swizzled source chunk
    const u16* aP = A  + (size_t)(m0 + r0) * K + w * 8;
    const u16* bP = BT + (size_t)(n0 + r0) * K + w * 8;

    for (int k0 = 0; k0 < K; k0 += 64) {
        __syncthreads();
#pragma unroll
        for (int u = 0; u < BM / 32; u++)
            load_lds16(aP + (size_t)(32 * u) * K + k0, &sm.s.As[(tid + 256 * u) * 8]);
#pragma unroll
        for (int u = 0; u < 4; u++)
            load_lds16(bP + (size_t)(32 * u) * K + k0, &sm.s.Bs[(tid + 256 * u) * 8]);
        __syncthreads();

#pragma unroll
        for (int kk = 0; kk < 4; kk++) {
            const int csel = ((kk * 2 + kh) ^ (l32 & 7)) * 8;
            frag_ab af[MT], bf[2];
#pragma unroll
            for (int t = 0; t < MT; t++)
                af[t] = *(const frag_ab*)&sm.s.As[(wm + t * 32 + l32) * 64 + csel];
#pragma unroll
            for (int t = 0; t < 2; t++)
                bf[t] = *(const frag_ab*)&sm.s.Bs[(wn + t * 32 + l32) * 64 + csel];
#pragma unroll
            for (int mt = 0; mt < MT; mt++)
#pragma unroll
                for (int nt = 0; nt < 2; nt++)
                    acc[mt][nt] = __builtin_amdgcn_mfma_f32_32x32x16_bf16(af[mt], bf[nt], acc[mt][nt], 0, 0, 0);
        }
    }

    if constexpr (BF16_OUT) {
        __syncthreads();
#pragma unroll
        for (int mt = 0; mt < MT; mt++)
#pragma unroll
            for (int nt = 0; nt < 2; nt++) {
                int col = wn + nt * 32 + l32;
#pragma unroll
                for (int reg = 0; reg < 16; reg++) {
                    int row = wm + mt * 32 + (reg & 3) + 8 * (reg >> 2) + 4 * kh;
                    sm.cs[row * 136 + col] = f2bf(acc[mt][nt][reg]);
                }
            }
        __syncthreads();
        const int cc = tid & 15, rb = tid >> 4;
#pragma unroll
        for (int i = 0; i < BM / 16; i++) {
            int row = rb + 16 * i;
            u16x8 vv = *(const u16x8*)&sm.cs[row * 136 + cc * 8];
            *(u16x8*)((u16*)C + (size_t)(m0 + row) * N + n0 + cc * 8) = vv;
        }
    } else {
#pragma unroll
        for (int mt = 0; mt < MT; mt++)
#pragma unroll
            for (int nt = 0; nt < 2; nt++) {
                int col = n0 + wn + nt * 32 + l32;
#pragma unroll
                for (int reg = 0; reg < 16; reg++) {
                    int row = m0 + wm + mt * 32 + (reg & 3) + 8 * (reg >> 2) + 4 * kh;
                    ((float*)C)[(size_t)row * N + col] = acc[mt][nt][reg];
                }
            }
    }
}

// ---------------- MFMA flash attention (sliding window), pipelined (r0-exact) ----------------
// Blocks [0,1024): attention, decode head=B&31, qc=B>>5 -> all 32 q-tiles of a
// head land on XCD head%8; per-XCD KV working set = 4 heads x 512 KB = 2 MB.
// Blocks [1024,2048): W_out transpose-cast (reuses Ks LDS; woutT consumed by gemm2).
__global__ __launch_bounds__(256) void attn_kernel(const u16* __restrict__ qkv, u16* __restrict__ out,
                                                   const float* __restrict__ W_out,
                                                   u16* __restrict__ woutT) {
    __shared__ u16 Ks[2][64 * 64];       // XOR-chunk-swizzled: chunk c of row r at c^(r&7)
    __shared__ u16 Vt[64 * 72];          // Vt[d][j], row pad +8 (single buffer)
    __shared__ u16 ps[4][16 * 72];       // per-wave P tile, row pad +8

    if (blockIdx.x >= 1024) {            // W_out transpose blocks
        int t = blockIdx.x - 1024;       // 1024 tiles of 32x32
        transpose_tile(W_out, woutT, D_MODEL, D_MODEL, (t & 31) * 32, (t >> 5) * 32,
                       0, 1.0f, (float(*)[33])&Ks[0][0]);
        return;
    }

    const int tid = threadIdx.x;
    const int wave = tid >> 6, lane = tid & 63;
    const int quad = lane >> 4, c16 = lane & 15;

    const int bh = blockIdx.x & 31;      // b*16+h  -> XCD = bh%8
    const int qc = blockIdx.x >> 5;      // 0..31
    const int h  = bh & 15;
    const int b  = bh >> 4;
    const int q0 = qc * 64;
    const int qw0 = q0 + wave * 16;

    frag_ab qf[2];
    {
        const u16* qrow = qkv + (size_t)(b * SEQ + qw0 + c16) * 3072 + h * 64;
        qf[0] = *(const frag_ab*)(qrow + quad * 8);
        qf[1] = *(const frag_ab*)(qrow + 32 + quad * 8);
    }

    float m_r[4], l_r[4];
    frag_cd acc[4] = {};

    const int ntiles = qc < 4 ? qc + 1 : 5;

    const int krow = wave * 16 + (lane >> 3);
    const int kchunk = (lane & 7) ^ (lane >> 3);
    const int vj2 = (tid & 31) * 2, vd8 = tid >> 5;

    const u16* kbase = qkv + (size_t)(b * SEQ + krow) * 3072 + 1024 + h * 64 + kchunk * 8;
    const u16* vbase = qkv + (size_t)(b * SEQ + vj2) * 3072 + 2048 + h * 64 + vd8 * 8;

    u16x8 va, vb;
    {
        const u16* g = kbase + (size_t)q0 * 3072;
        load_lds16(g,            &Ks[0][krow * 64 + (lane & 7) * 8]);
        load_lds16(g + 8 * 3072, &Ks[0][(krow + 8) * 64 + (lane & 7) * 8]);
        const u16* gv = vbase + (size_t)q0 * 3072;
        va = *(const u16x8*)gv;
        vb = *(const u16x8*)(gv + 3072);
#pragma unroll
        for (int dd = 0; dd < 8; dd++)
            *(u32*)&Vt[(vd8 * 8 + dd) * 72 + vj2] = (u32)va[dd] | ((u32)vb[dd] << 16);
    }

    for (int t = 0; t < ntiles; t++) {
        const int cur = t & 1, nxt = cur ^ 1;
        const int j0 = q0 - 64 * t;
        __syncthreads();                 // Ks[cur] + Vt staged & visible
        const bool pre = (t + 1 < ntiles);
        if (pre) {                       // prefetch t+1: K -> LDS[nxt] (async), V -> regs
            const u16* g = kbase + (size_t)(j0 - 64) * 3072;
            load_lds16(g,            &Ks[nxt][krow * 64 + (lane & 7) * 8]);
            load_lds16(g + 8 * 3072, &Ks[nxt][(krow + 8) * 64 + (lane & 7) * 8]);
            const u16* gv = vbase + (size_t)(j0 - 64) * 3072;
            va = *(const u16x8*)gv;
            vb = *(const u16x8*)(gv + 3072);
        }

        frag_cd s[4] = {};
#pragma unroll
        for (int kb = 0; kb < 4; kb++) {
            frag_ab kf0 = *(const frag_ab*)&Ks[cur][(kb * 16 + c16) * 64 + ((quad    ) ^ (c16 & 7)) * 8];
            frag_ab kf1 = *(const frag_ab*)&Ks[cur][(kb * 16 + c16) * 64 + ((4 + quad) ^ (c16 & 7)) * 8];
            s[kb] = __builtin_amdgcn_mfma_f32_16x16x32_bf16(qf[0], kf0, s[kb], 0, 0, 0);
            s[kb] = __builtin_amdgcn_mfma_f32_16x16x32_bf16(qf[1], kf1, s[kb], 0, 0, 0);
        }

        if (t == 0) {
#pragma unroll
            for (int reg = 0; reg < 4; reg++) {
                const int i = qw0 + quad * 4 + reg;
#pragma unroll
                for (int kb = 0; kb < 4; kb++)
                    if (q0 + kb * 16 + c16 > i) s[kb][reg] = -1e30f;
            }
        } else if (t == 4) {
#pragma unroll
            for (int reg = 0; reg < 4; reg++) {
                const int i = qw0 + quad * 4 + reg;
#pragma unroll
                for (int kb = 0; kb < 4; kb++)
                    if (j0 + kb * 16 + c16 + WIN <= i) s[kb][reg] = -1e30f;
            }
        }

        float mt_[4];
#pragma unroll
        for (int reg = 0; reg < 4; reg++)
            mt_[reg] = fmaxf(fmaxf(s[0][reg], s[1][reg]), fmaxf(s[2][reg], s[3][reg]));
#pragma unroll
        for (int off = 1; off < 16; off <<= 1)
#pragma unroll
            for (int reg = 0; reg < 4; reg++) mt_[reg] = fmaxf(mt_[reg], __shfl_xor(mt_[reg], off));

        float alpha[4];
        if (t == 0) {
#pragma unroll
            for (int reg = 0; reg < 4; reg++) m_r[reg] = mt_[reg];
        } else {
#pragma unroll
            for (int reg = 0; reg < 4; reg++) {
                float mn = fmaxf(m_r[reg], mt_[reg]);
                alpha[reg] = __builtin_amdgcn_exp2f(m_r[reg] - mn);
                m_r[reg] = mn;
            }
        }

        float rs[4] = {0.f, 0.f, 0.f, 0.f};
#pragma unroll
        for (int kb = 0; kb < 4; kb++)
#pragma unroll
            for (int reg = 0; reg < 4; reg++) {
                float p = __builtin_amdgcn_exp2f(s[kb][reg] - m_r[reg]);
                union { float f; u32 u; } pu; pu.f = p;
                ps[wave][(quad * 4 + reg) * 72 + kb * 16 + c16] = (u16)(pu.u >> 16);  // RTZ
                rs[reg] += p;
            }
#pragma unroll
        for (int off = 1; off < 16; off <<= 1)
#pragma unroll
            for (int reg = 0; reg < 4; reg++) rs[reg] += __shfl_xor(rs[reg], off);

        if (t == 0) {
#pragma unroll
            for (int reg = 0; reg < 4; reg++) l_r[reg] = rs[reg];
        } else {
#pragma unroll
            for (int reg = 0; reg < 4; reg++) l_r[reg] = l_r[reg] * alpha[reg] + rs[reg];
#pragma unroll
            for (int dblk = 0; dblk < 4; dblk++)
#pragma unroll
                for (int reg = 0; reg < 4; reg++) acc[dblk][reg] *= alpha[reg];
        }

#pragma unroll
        for (int js = 0; js < 2; js++) {
            frag_ab pf = *(const frag_ab*)&ps[wave][c16 * 72 + js * 32 + quad * 8];
#pragma unroll
            for (int dblk = 0; dblk < 4; dblk++) {
                frag_ab vf = *(const frag_ab*)&Vt[(dblk * 16 + c16) * 72 + js * 32 + quad * 8];
                acc[dblk] = __builtin_amdgcn_mfma_f32_16x16x32_bf16(pf, vf, acc[dblk], 0, 0, 0);
            }
        }

        if (pre) {
            __syncthreads();             // all waves done with PV(t) -> Vt overwrite safe
#pragma unroll
            for (int dd = 0; dd < 8; dd++)
                *(u32*)&Vt[(vd8 * 8 + dd) * 72 + vj2] = (u32)va[dd] | ((u32)vb[dd] << 16);
        }
    }

    float inv[4];
#pragma unroll
    for (int reg = 0; reg < 4; reg++) inv[reg] = 1.f / l_r[reg];
#pragma unroll
    for (int dblk = 0; dblk < 4; dblk++)
#pragma unroll
        for (int reg = 0; reg < 4; reg++)
            out[(size_t)(b * SEQ + qw0 + quad * 4 + reg) * 1024 + h * 64 + dblk * 16 + c16] =
                f2bf(acc[dblk][reg] * inv[reg]);
}

extern "C" void kernel_launch(void* const* d_in, const int* in_sizes, int n_in,
                              void* d_out, int out_size, void* d_ws, size_t ws_size,
                              hipStream_t stream) {
    const float* x     = (const float*)d_in[0];   // [2,2048,1024]
    const float* W_qkv = (const float*)d_in[1];   // [1024,3072]
    const float* W_out = (const float*)d_in[2];   // [1024,1024]
    float* out = (float*)d_out;                   // [2,2048,1024]

    char* ws = (char*)d_ws;
    u16* xb    = (u16*)(ws);                       //  8 MB : x bf16 [4096,1024]
    u16* wqkvT = (u16*)(ws + 8388608);             //  6 MB : W_qkv^T bf16 [3072,1024] (q rows pre-scaled)
    u16* woutT = (u16*)(ws + 14680064);            //  2 MB : W_out^T bf16 [1024,1024]
    u16* qkvb  = (u16*)(ws + 16777216);            // 24 MB : qkv bf16 [4096,3072]
    u16* attnb = (u16*)(ws + 41943040);            //  8 MB : attn out bf16 [4096,1024]

    const float QSCALE = 0.125f * 1.4426950408889634f;  // 1/sqrt(64) * log2(e)

    prep_kernel<<<7168, 256, 0, stream>>>(x, W_qkv, xb, wqkvT, QSCALE);
    // gemm1: 16x16x32 4x3-blocked, BM=128/BN=96, 1024 blocks = 4/CU, XCD-swizzled.
    gemm1_96<<<1024, 256, 0, stream>>>(xb, wqkvT, qkvb);
    // attn (1024 blocks, head-per-XCD swizzle) + W_out transpose (1024 blocks) [r0-exact]
    attn_kernel<<<2048, 256, 0, stream>>>(qkvb, attnb, W_out, woutT);
    // gemm2: out = attnb @ woutT^T. 512 blocks, BM=64, 2/CU [r0-exact].
    gemm_bk64<false, 64, 64, 1><<<512, 256, 0, stream>>>(
        attnb, woutT, out, NROWS, D_MODEL, D_MODEL);
}

// Round 7
// 146.628 us; speedup vs baseline: 1.7259x; 1.0091x over previous
//
#include <hip/hip_runtime.h>

typedef unsigned short u16;
typedef unsigned int u32;

#define D_MODEL 1024
#define N_HEADS 16
#define D_HEAD 64
#define WIN 256
#define SEQ 2048
#define BATCH 2
#define NROWS (BATCH*SEQ)          // 4096 token rows

typedef short frag_ab __attribute__((ext_vector_type(8)));   // 8 bf16 (4 VGPRs)
typedef float frag_cd __attribute__((ext_vector_type(4)));   // 4 fp32 (16x16 C/D)
typedef float f32x16 __attribute__((ext_vector_type(16)));   // 32x32 C/D
typedef u16 u16x8 __attribute__((ext_vector_type(8)));

__device__ __forceinline__ u16 f2bf(float f) {
    union { float f; u32 u; } x; x.f = f;
    u32 r = x.u + 0x7fffu + ((x.u >> 16) & 1u);   // RNE
    return (u16)(r >> 16);
}

__device__ __forceinline__ void load_lds16(const void* g, void* l) {
    __builtin_amdgcn_global_load_lds(
        (const __attribute__((address_space(1))) void*)g,
        (__attribute__((address_space(3))) void*)l, 16, 0, 0);
}

// ---------------- transpose-cast tile helper (caller supplies LDS) ----------------
__device__ __forceinline__ void transpose_tile(const float* __restrict__ W, u16* __restrict__ WT,
                                               int K, int N, int n0, int k0,
                                               int scale_rows, float scale, float (*tile)[33]) {
    int x = threadIdx.x & 31, y = threadIdx.x >> 5;   // 32 x 8
#pragma unroll
    for (int r = 0; r < 4; r++)
        tile[y + 8 * r][x] = W[(size_t)(k0 + y + 8 * r) * N + n0 + x];
    __syncthreads();
#pragma unroll
    for (int r = 0; r < 4; r++) {
        int nrow = n0 + y + 8 * r;
        float v = tile[x][y + 8 * r];
        if (nrow < scale_rows) v *= scale;
        WT[(size_t)nrow * K + k0 + x] = f2bf(v);
    }
}

// ---------------- prep: cast x + transpose-cast W_qkv (r0-exact) ----------------
__global__ __launch_bounds__(256) void prep_kernel(const float* __restrict__ x,
                                                   const float* __restrict__ W_qkv,
                                                   u16* __restrict__ xb,
                                                   u16* __restrict__ wqkvT,
                                                   float qscale) {
    __shared__ float tile[32][33];
    const int bid = blockIdx.x;
    if (bid < 4096) {
        int idx = bid * 256 + threadIdx.x;
        float4 v = ((const float4*)x)[idx];
        ushort4 o;
        o.x = f2bf(v.x); o.y = f2bf(v.y); o.z = f2bf(v.z); o.w = f2bf(v.w);
        ((ushort4*)xb)[idx] = o;
    } else {
        int t = bid - 4096;                       // N=3072: 96 x 32 tiles
        transpose_tile(W_qkv, wqkvT, D_MODEL, 3 * D_MODEL, (t % 96) * 32, (t / 96) * 32,
                       D_MODEL, qscale, tile);
    }
}

// ---------------- gemm1: qkv = xb @ wqkvT^T. BM=128, BN=96, 16x16x32 frags (r6-exact) ----------------
// 4x3 per-wave blocking: 7 ds_read_b128 / 12 MFMA = 0.58 reads/MFMA; 1024 blocks = 4/CU.
// A/B frag: lane m=c16, k=quad*8+j per 32-slice; LDS slot of chunk c at row r = c^(r&7).
// C/D: col=lane&15, row=quad*4+reg [m89/m91].
__global__ __launch_bounds__(256, 4) void gemm1_96(const u16* __restrict__ A,
                                                   const u16* __restrict__ BT,
                                                   u16* __restrict__ C) {
    constexpr int K = 1024, N = 3072;
    __shared__ union SMem {
        struct { u16 As[128 * 64]; u16 Bs[96 * 64]; } s;   // 16 KB + 12 KB
        u16 cs[128 * 104];                                 // epilogue transpose (26.6 KB)
    } sm;
    const int tid = threadIdx.x;
    const int xcd = blockIdx.x & 7, sblk = blockIdx.x >> 3;
    const int m0 = (sblk & 31) * 128;                 // 32 m-blocks
    const int n0 = (xcd * 4 + (sblk >> 5)) * 96;      // 8 XCD x 4 n-blocks (B-panel 768 KB/XCD)
    const int wave = tid >> 6, lane = tid & 63;
    const int quad = lane >> 4, c16 = lane & 15;
    const int wm = (wave >> 1) * 64, wn = (wave & 1) * 48;

    const int r0 = tid >> 3;                   // 0..31
    const int w  = (tid & 7) ^ (r0 & 7);       // swizzled source chunk
    const u16* aP = A  + (size_t)(m0 + r0) * K + w * 8;
    const u16* bP = BT + (size_t)(n0 + r0) * K + w * 8;

    frag_cd acc[4][3] = {};                    // 4x3 of 16x16 -> 64x48 per wave

    for (int k0 = 0; k0 < K; k0 += 64) {
        __syncthreads();                       // WAR: prev iteration's reads done
#pragma unroll
        for (int u = 0; u < 4; u++)            // A: 128 rows
            load_lds16(aP + (size_t)(32 * u) * K + k0, &sm.s.As[(tid + 256 * u) * 8]);
#pragma unroll
        for (int u = 0; u < 3; u++)            // B: 96 rows
            load_lds16(bP + (size_t)(32 * u) * K + k0, &sm.s.Bs[(tid + 256 * u) * 8]);
        __syncthreads();                       // deposits visible

#pragma unroll
        for (int kk = 0; kk < 2; kk++) {       // two K=32 slices
            const int csel = ((kk * 4 + quad) ^ (c16 & 7)) * 8;
            frag_ab af[4], bf[3];
#pragma unroll
            for (int fm = 0; fm < 4; fm++)
                af[fm] = *(const frag_ab*)&sm.s.As[(wm + fm * 16 + c16) * 64 + csel];
#pragma unroll
            for (int fn = 0; fn < 3; fn++)
                bf[fn] = *(const frag_ab*)&sm.s.Bs[(wn + fn * 16 + c16) * 64 + csel];
#pragma unroll
            for (int fm = 0; fm < 4; fm++)
#pragma unroll
                for (int fn = 0; fn < 3; fn++)
                    acc[fm][fn] = __builtin_amdgcn_mfma_f32_16x16x32_bf16(
                        af[fm], bf[fn], acc[fm][fn], 0, 0, 0);
        }
    }

    // epilogue: acc -> LDS (row-major bf16) -> vectorized store
    __syncthreads();
#pragma unroll
    for (int fm = 0; fm < 4; fm++)
#pragma unroll
        for (int fn = 0; fn < 3; fn++) {
            const int col = wn + fn * 16 + c16;
#pragma unroll
            for (int reg = 0; reg < 4; reg++) {
                const int row = wm + fm * 16 + quad * 4 + reg;   // C/D map m89/m91
                sm.cs[row * 104 + col] = f2bf(acc[fm][fn][reg]);
            }
        }
    __syncthreads();
#pragma unroll
    for (int i = 0; i < 6; i++) {              // 128 rows x 12 chunks of 8
        const int idx = tid + 256 * i;
        const int row = idx / 12, c8 = idx % 12;
        u16x8 vv = *(const u16x8*)&sm.cs[row * 104 + c8 * 8];
        *(u16x8*)(C + (size_t)(m0 + row) * N + n0 + c8 * 8) = vv;
    }
}

// ---------------- gemm2: out = attnb @ woutT^T. BM=64, BN=128, 16x16x32 frags ----------------
// Theory (r7): r0's gemm2 ran 32x32 MT=1 -> 1.0 ds_read/MFMA (the inefficiency r6
// fixed in gemm1). Same 2-barrier template, same grid (512 blk = 2/CU), same staging
// (2+4 loads/thread), but 16x16 frags with per-wave 64x32 tile (fm=4 x fn=2):
// 6 reads / 8 MFMA = 0.75. Frag maps identical to gemm1_96 (verified r6).
// Decode: xcd=bid&7 -> n0=xcd*128 (B-panel 256 KB/XCD, L2-resident); m0=(bid>>3)*64.
__global__ __launch_bounds__(256, 4) void gemm2_64(const u16* __restrict__ A,
                                                   const u16* __restrict__ BT,
                                                   float* __restrict__ C) {
    constexpr int K = 1024, N = 1024;
    __shared__ struct { u16 As[64 * 64]; u16 Bs[128 * 64]; } sm;   // 8 KB + 16 KB
    const int tid = threadIdx.x;
    const int xcd = blockIdx.x & 7, sblk = blockIdx.x >> 3;
    const int m0 = sblk * 64;                  // 64 m-blocks
    const int n0 = xcd * 128;                  // 8 XCDs x 128 cols
    const int wave = tid >> 6, lane = tid & 63;
    const int quad = lane >> 4, c16 = lane & 15;
    const int wn = wave * 32;                  // 4 waves span BN=128; all share A rows

    const int r0 = tid >> 3;                   // 0..31
    const int w  = (tid & 7) ^ (r0 & 7);       // swizzled source chunk
    const u16* aP = A  + (size_t)(m0 + r0) * K + w * 8;
    const u16* bP = BT + (size_t)(n0 + r0) * K + w * 8;

    frag_cd acc[4][2] = {};                    // 4m x 2n of 16x16 -> 64x32 per wave

    for (int k0 = 0; k0 < K; k0 += 64) {
        __syncthreads();
#pragma unroll
        for (int u = 0; u < 2; u++)            // A: 64 rows
            load_lds16(aP + (size_t)(32 * u) * K + k0, &sm.As[(tid + 256 * u) * 8]);
#pragma unroll
        for (int u = 0; u < 4; u++)            // B: 128 rows
            load_lds16(bP + (size_t)(32 * u) * K + k0, &sm.Bs[(tid + 256 * u) * 8]);
        __syncthreads();

#pragma unroll
        for (int kk = 0; kk < 2; kk++) {       // two K=32 slices
            const int csel = ((kk * 4 + quad) ^ (c16 & 7)) * 8;
            frag_ab af[4], bf[2];
#pragma unroll
            for (int fm = 0; fm < 4; fm++)
                af[fm] = *(const frag_ab*)&sm.As[(fm * 16 + c16) * 64 + csel];
#pragma unroll
            for (int fn = 0; fn < 2; fn++)
                bf[fn] = *(const frag_ab*)&sm.Bs[(wn + fn * 16 + c16) * 64 + csel];
#pragma unroll
            for (int fm = 0; fm < 4; fm++)
#pragma unroll
                for (int fn = 0; fn < 2; fn++)
                    acc[fm][fn] = __builtin_amdgcn_mfma_f32_16x16x32_bf16(
                        af[fm], bf[fn], acc[fm][fn], 0, 0, 0);
        }
    }

    // epilogue: direct f32 stores (16 lanes x 4 B = 64-B segments)
#pragma unroll
    for (int fm = 0; fm < 4; fm++)
#pragma unroll
        for (int fn = 0; fn < 2; fn++) {
            const int col = n0 + wn + fn * 16 + c16;
#pragma unroll
            for (int reg = 0; reg < 4; reg++) {
                const int row = m0 + fm * 16 + quad * 4 + reg;   // C/D map m89/m91
                C[(size_t)row * N + col] = acc[fm][fn][reg];
            }
        }
}

// ---------------- MFMA flash attention (sliding window), pipelined (r0-exact) ----------------
// Blocks [0,1024): attention, decode head=B&31, qc=B>>5 -> all 32 q-tiles of a
// head land on XCD head%8; per-XCD KV working set = 4 heads x 512 KB = 2 MB.
// Blocks [1024,2048): W_out transpose-cast (reuses Ks LDS; woutT consumed by gemm2).
__global__ __launch_bounds__(256) void attn_kernel(const u16* __restrict__ qkv, u16* __restrict__ out,
                                                   const float* __restrict__ W_out,
                                                   u16* __restrict__ woutT) {
    __shared__ u16 Ks[2][64 * 64];       // XOR-chunk-swizzled: chunk c of row r at c^(r&7)
    __shared__ u16 Vt[64 * 72];          // Vt[d][j], row pad +8 (single buffer)
    __shared__ u16 ps[4][16 * 72];       // per-wave P tile, row pad +8

    if (blockIdx.x >= 1024) {            // W_out transpose blocks
        int t = blockIdx.x - 1024;       // 1024 tiles of 32x32
        transpose_tile(W_out, woutT, D_MODEL, D_MODEL, (t & 31) * 32, (t >> 5) * 32,
                       0, 1.0f, (float(*)[33])&Ks[0][0]);
        return;
    }

    const int tid = threadIdx.x;
    const int wave = tid >> 6, lane = tid & 63;
    const int quad = lane >> 4, c16 = lane & 15;

    const int bh = blockIdx.x & 31;      // b*16+h  -> XCD = bh%8
    const int qc = blockIdx.x >> 5;      // 0..31
    const int h  = bh & 15;
    const int b  = bh >> 4;
    const int q0 = qc * 64;
    const int qw0 = q0 + wave * 16;

    frag_ab qf[2];
    {
        const u16* qrow = qkv + (size_t)(b * SEQ + qw0 + c16) * 3072 + h * 64;
        qf[0] = *(const frag_ab*)(qrow + quad * 8);
        qf[1] = *(const frag_ab*)(qrow + 32 + quad * 8);
    }

    float m_r[4], l_r[4];
    frag_cd acc[4] = {};

    const int ntiles = qc < 4 ? qc + 1 : 5;

    const int krow = wave * 16 + (lane >> 3);
    const int kchunk = (lane & 7) ^ (lane >> 3);
    const int vj2 = (tid & 31) * 2, vd8 = tid >> 5;

    const u16* kbase = qkv + (size_t)(b * SEQ + krow) * 3072 + 1024 + h * 64 + kchunk * 8;
    const u16* vbase = qkv + (size_t)(b * SEQ + vj2) * 3072 + 2048 + h * 64 + vd8 * 8;

    u16x8 va, vb;
    {
        const u16* g = kbase + (size_t)q0 * 3072;
        load_lds16(g,            &Ks[0][krow * 64 + (lane & 7) * 8]);
        load_lds16(g + 8 * 3072, &Ks[0][(krow + 8) * 64 + (lane & 7) * 8]);
        const u16* gv = vbase + (size_t)q0 * 3072;
        va = *(const u16x8*)gv;
        vb = *(const u16x8*)(gv + 3072);
#pragma unroll
        for (int dd = 0; dd < 8; dd++)
            *(u32*)&Vt[(vd8 * 8 + dd) * 72 + vj2] = (u32)va[dd] | ((u32)vb[dd] << 16);
    }

    for (int t = 0; t < ntiles; t++) {
        const int cur = t & 1, nxt = cur ^ 1;
        const int j0 = q0 - 64 * t;
        __syncthreads();                 // Ks[cur] + Vt staged & visible
        const bool pre = (t + 1 < ntiles);
        if (pre) {                       // prefetch t+1: K -> LDS[nxt] (async), V -> regs
            const u16* g = kbase + (size_t)(j0 - 64) * 3072;
            load_lds16(g,            &Ks[nxt][krow * 64 + (lane & 7) * 8]);
            load_lds16(g + 8 * 3072, &Ks[nxt][(krow + 8) * 64 + (lane & 7) * 8]);
            const u16* gv = vbase + (size_t)(j0 - 64) * 3072;
            va = *(const u16x8*)gv;
            vb = *(const u16x8*)(gv + 3072);
        }

        frag_cd s[4] = {};
#pragma unroll
        for (int kb = 0; kb < 4; kb++) {
            frag_ab kf0 = *(const frag_ab*)&Ks[cur][(kb * 16 + c16) * 64 + ((quad    ) ^ (c16 & 7)) * 8];
            frag_ab kf1 = *(const frag_ab*)&Ks[cur][(kb * 16 + c16) * 64 + ((4 + quad) ^ (c16 & 7)) * 8];
            s[kb] = __builtin_amdgcn_mfma_f32_16x16x32_bf16(qf[0], kf0, s[kb], 0, 0, 0);
            s[kb] = __builtin_amdgcn_mfma_f32_16x16x32_bf16(qf[1], kf1, s[kb], 0, 0, 0);
        }

        if (t == 0) {
#pragma unroll
            for (int reg = 0; reg < 4; reg++) {
                const int i = qw0 + quad * 4 + reg;
#pragma unroll
                for (int kb = 0; kb < 4; kb++)
                    if (q0 + kb * 16 + c16 > i) s[kb][reg] = -1e30f;
            }
        } else if (t == 4) {
#pragma unroll
            for (int reg = 0; reg < 4; reg++) {
                const int i = qw0 + quad * 4 + reg;
#pragma unroll
                for (int kb = 0; kb < 4; kb++)
                    if (j0 + kb * 16 + c16 + WIN <= i) s[kb][reg] = -1e30f;
            }
        }

        float mt_[4];
#pragma unroll
        for (int reg = 0; reg < 4; reg++)
            mt_[reg] = fmaxf(fmaxf(s[0][reg], s[1][reg]), fmaxf(s[2][reg], s[3][reg]));
#pragma unroll
        for (int off = 1; off < 16; off <<= 1)
#pragma unroll
            for (int reg = 0; reg < 4; reg++) mt_[reg] = fmaxf(mt_[reg], __shfl_xor(mt_[reg], off));

        float alpha[4];
        if (t == 0) {
#pragma unroll
            for (int reg = 0; reg < 4; reg++) m_r[reg] = mt_[reg];
        } else {
#pragma unroll
            for (int reg = 0; reg < 4; reg++) {
                float mn = fmaxf(m_r[reg], mt_[reg]);
                alpha[reg] = __builtin_amdgcn_exp2f(m_r[reg] - mn);
                m_r[reg] = mn;
            }
        }

        float rs[4] = {0.f, 0.f, 0.f, 0.f};
#pragma unroll
        for (int kb = 0; kb < 4; kb++)
#pragma unroll
            for (int reg = 0; reg < 4; reg++) {
                float p = __builtin_amdgcn_exp2f(s[kb][reg] - m_r[reg]);
                union { float f; u32 u; } pu; pu.f = p;
                ps[wave][(quad * 4 + reg) * 72 + kb * 16 + c16] = (u16)(pu.u >> 16);  // RTZ
                rs[reg] += p;
            }
#pragma unroll
        for (int off = 1; off < 16; off <<= 1)
#pragma unroll
            for (int reg = 0; reg < 4; reg++) rs[reg] += __shfl_xor(rs[reg], off);

        if (t == 0) {
#pragma unroll
            for (int reg = 0; reg < 4; reg++) l_r[reg] = rs[reg];
        } else {
#pragma unroll
            for (int reg = 0; reg < 4; reg++) l_r[reg] = l_r[reg] * alpha[reg] + rs[reg];
#pragma unroll
            for (int dblk = 0; dblk < 4; dblk++)
#pragma unroll
                for (int reg = 0; reg < 4; reg++) acc[dblk][reg] *= alpha[reg];
        }

#pragma unroll
        for (int js = 0; js < 2; js++) {
            frag_ab pf = *(const frag_ab*)&ps[wave][c16 * 72 + js * 32 + quad * 8];
#pragma unroll
            for (int dblk = 0; dblk < 4; dblk++) {
                frag_ab vf = *(const frag_ab*)&Vt[(dblk * 16 + c16) * 72 + js * 32 + quad * 8];
                acc[dblk] = __builtin_amdgcn_mfma_f32_16x16x32_bf16(pf, vf, acc[dblk], 0, 0, 0);
            }
        }

        if (pre) {
            __syncthreads();             // all waves done with PV(t) -> Vt overwrite safe
#pragma unroll
            for (int dd = 0; dd < 8; dd++)
                *(u32*)&Vt[(vd8 * 8 + dd) * 72 + vj2] = (u32)va[dd] | ((u32)vb[dd] << 16);
        }
    }

    float inv[4];
#pragma unroll
    for (int reg = 0; reg < 4; reg++) inv[reg] = 1.f / l_r[reg];
#pragma unroll
    for (int dblk = 0; dblk < 4; dblk++)
#pragma unroll
        for (int reg = 0; reg < 4; reg++)
            out[(size_t)(b * SEQ + qw0 + quad * 4 + reg) * 1024 + h * 64 + dblk * 16 + c16] =
                f2bf(acc[dblk][reg] * inv[reg]);
}

extern "C" void kernel_launch(void* const* d_in, const int* in_sizes, int n_in,
                              void* d_out, int out_size, void* d_ws, size_t ws_size,
                              hipStream_t stream) {
    const float* x     = (const float*)d_in[0];   // [2,2048,1024]
    const float* W_qkv = (const float*)d_in[1];   // [1024,3072]
    const float* W_out = (const float*)d_in[2];   // [1024,1024]
    float* out = (float*)d_out;                   // [2,2048,1024]

    char* ws = (char*)d_ws;
    u16* xb    = (u16*)(ws);                       //  8 MB : x bf16 [4096,1024]
    u16* wqkvT = (u16*)(ws + 8388608);             //  6 MB : W_qkv^T bf16 [3072,1024] (q rows pre-scaled)
    u16* woutT = (u16*)(ws + 14680064);            //  2 MB : W_out^T bf16 [1024,1024]
    u16* qkvb  = (u16*)(ws + 16777216);            // 24 MB : qkv bf16 [4096,3072]
    u16* attnb = (u16*)(ws + 41943040);            //  8 MB : attn out bf16 [4096,1024]

    const float QSCALE = 0.125f * 1.4426950408889634f;  // 1/sqrt(64) * log2(e)

    prep_kernel<<<7168, 256, 0, stream>>>(x, W_qkv, xb, wqkvT, QSCALE);
    // gemm1: 16x16x32 4x3-blocked, BM=128/BN=96, 1024 blocks = 4/CU [r6-proven].
    gemm1_96<<<1024, 256, 0, stream>>>(xb, wqkvT, qkvb);
    // attn (1024 blocks, head-per-XCD swizzle) + W_out transpose (1024 blocks) [r0-exact]
    attn_kernel<<<2048, 256, 0, stream>>>(qkvb, attnb, W_out, woutT);
    // gemm2: 16x16x32 4x2-blocked, BM=64/BN=128, 512 blocks = 2/CU (was 32x32 MT=1).
    gemm2_64<<<512, 256, 0, stream>>>(attnb, woutT, out);
}